// Round 19
// baseline (160.235 us; speedup 1.0000x reference)
//
#include <hip/hip_runtime.h>

#define NN 40000
#define NE 640000
#define NG 64
#define SCAN_NB ((NN + 255) / 256)   // 157 blocks
#define CCAP 768                     // LDS col-staging chunk

typedef unsigned short ushort_t;

__device__ __forceinline__ float fcomp(const float4& v, int t) {
    return t == 0 ? v.x : t == 1 ? v.y : t == 2 ? v.z : v.w;
}
// ---- bf16 pack/unpack (RNE) ----
__device__ __forceinline__ unsigned int pack2bf(float a, float b) {
    unsigned int ua = __float_as_uint(a);
    unsigned int ub = __float_as_uint(b);
    ua = (ua + 0x7fffu + ((ua >> 16) & 1u)) >> 16;
    ub = (ub + 0x7fffu + ((ub >> 16) & 1u)) >> 16;
    return ua | (ub << 16);
}
__device__ __forceinline__ uint2 pack4bf(const float4& v) {
    return make_uint2(pack2bf(v.x, v.y), pack2bf(v.z, v.w));
}
__device__ __forceinline__ float lo2f(unsigned int u) { return __uint_as_float(u << 16); }
__device__ __forceinline__ float hi2f(unsigned int u) { return __uint_as_float(u & 0xffff0000u); }
__device__ __forceinline__ float4 unp4(const uint2& u) {
    float4 r; r.x = lo2f(u.x); r.y = hi2f(u.x); r.z = lo2f(u.y); r.w = hi2f(u.y); return r;
}
// accumulate 8 bf16 (one uint4) into two float4s
__device__ __forceinline__ void acc8(const uint4& u, float4& lo, float4& hi) {
    lo.x += lo2f(u.x); lo.y += hi2f(u.x); lo.z += lo2f(u.y); lo.w += hi2f(u.y);
    hi.x += lo2f(u.z); hi.y += hi2f(u.z); hi.z += lo2f(u.w); hi.w += hi2f(u.w);
}
// ---- fp8 e4m3 (HW converts; OCP on gfx950) ----
typedef __attribute__((ext_vector_type(2))) float f32x2;
__device__ __forceinline__ unsigned int pack4fp8(const float4& v) {
    unsigned int r = 0;
    r = __builtin_amdgcn_cvt_pk_fp8_f32(v.x, v.y, r, false);
    r = __builtin_amdgcn_cvt_pk_fp8_f32(v.z, v.w, r, true);
    return r;
}
__device__ __forceinline__ void accf8x4(unsigned int u, float4& a) {
    f32x2 lo = __builtin_amdgcn_cvt_pk_f32_fp8(u, false);
    f32x2 hi = __builtin_amdgcn_cvt_pk_f32_fp8(u, true);
    a.x += lo[0]; a.y += lo[1]; a.z += hi[0]; a.w += hi[1];
}
// ---- device-wide sync for co-resident grids (counter zeroed per launch) ----
__device__ __forceinline__ void gsync(int* cnt, int nblk) {
    __syncthreads();
    if (threadIdx.x == 0) {
        __threadfence();
        atomicAdd(cnt, 1);
        while (atomicAdd(cnt, 0) < nblk) { __builtin_amdgcn_s_sleep(2); }
        __threadfence();
    }
    __syncthreads();
}

// ===== zero scratch: deg + sums + counts + ctr + 2 sync counters =====
__global__ __launch_bounds__(256) void zero_kernel(int* __restrict__ p, int n) {
    int i = blockIdx.x * 256 + threadIdx.x;
    if (i < n) p[i] = 0;
}

// ===== csr1: hist(epos) + x->bf16 conversion + fold Wfc through L4 =====
__global__ void csr1_kernel(const int* __restrict__ dst, int* __restrict__ deg,
                            int* __restrict__ epos,
                            const float4* __restrict__ x4, uint2* __restrict__ xb,
                            const float* __restrict__ W4rel,
                            const float* __restrict__ W4root,
                            const float* __restrict__ b4,
                            const float* __restrict__ Wfc,
                            float* __restrict__ wf) {
    int e = blockIdx.x * blockDim.x + threadIdx.x;
    if (e < NE) epos[e] = atomicAdd(&deg[dst[e]], 1);
    if (e < NN * 8) xb[e] = pack4bf(x4[e]);
    if (blockIdx.x == 0) {
        int t = threadIdx.x;
        if (t < 32) {
            float a = 0.f, b = 0.f;
#pragma unroll
            for (int j = 0; j < 16; ++j) {
                float w = Wfc[j];
                a += W4rel[t * 16 + j] * w;
                b += W4root[t * 16 + j] * w;
            }
            wf[t] = a;
            wf[32 + t] = b;
        } else if (t == 32) {
            float s = 0.f;
#pragma unroll
            for (int j = 0; j < 16; ++j) s += b4[j] * Wfc[j];
            wf[64] = s;
        }
    }
}

// ===== csr2: scan1 -> gsync -> scan23 -> gsync -> fill (157 blocks, all resident) =====
__global__ __launch_bounds__(256) void csr2_kernel(
        const int* __restrict__ deg,
        int* __restrict__ rowptr,
        int* __restrict__ bsum,
        const int* __restrict__ src, const int* __restrict__ dst,
        const int* __restrict__ epos,
        ushort_t* __restrict__ col,
        int* __restrict__ sc) {           // 2 sync counters
    __shared__ int ws[4];
    __shared__ int wpre[4];
    int t = threadIdx.x, b = blockIdx.x;
    int lane = t & 63, wid = t >> 6;
    // ---- P1: per-block exclusive scan + block sum ----
    {
        int i = b * 256 + t;
        int v = (i < NN) ? deg[i] : 0;
        int incl = v;
#pragma unroll
        for (int off = 1; off < 64; off <<= 1) {
            int u = __shfl_up(incl, off, 64);
            if (lane >= off) incl += u;
        }
        if (lane == 63) ws[wid] = incl;
        __syncthreads();
        if (t == 0) {
            int s = 0;
#pragma unroll
            for (int w = 0; w < 4; ++w) { wpre[w] = s; s += ws[w]; }
            bsum[b] = s;
        }
        __syncthreads();
        if (i < NN) rowptr[i] = wpre[wid] + (incl - v);
    }
    gsync(&sc[0], SCAN_NB);
    // ---- P2: add prefix of block sums ----
    {
        int v = (t < b) ? bsum[t] : 0;
#pragma unroll
        for (int off = 32; off; off >>= 1) v += __shfl_xor(v, off, 64);
        if (lane == 0) ws[wid] = v;
        __syncthreads();
        int soff = ws[0] + ws[1] + ws[2] + ws[3];
        int i = b * 256 + t;
        if (i < NN) rowptr[i] += soff;
        if (b == SCAN_NB - 1 && t == 0) rowptr[NN] = soff + bsum[b];
    }
    gsync(&sc[1], SCAN_NB);
    // ---- P3: fill (grid-stride) ----
    for (int e = b * 256 + t; e < NE; e += SCAN_NB * 256)
        col[rowptr[dst[e]] + epos[e]] = (ushort_t)src[e];
}

// ====== fused L1: gather xb (uint4-wide bf16) + conv 32->128, h1 out bf16 ======
__global__ __launch_bounds__(256, 4) void fconv1_kernel(
        const uint4* __restrict__ xb4,     // N x 4 (bf16x8)
        const float4* __restrict__ x,      // N x 8 (fp32, root term)
        const int* __restrict__ rowptr,
        const ushort_t* __restrict__ col,
        const float4* __restrict__ Wrel,
        const float4* __restrict__ Wroot,
        const float4* __restrict__ bias,
        uint2* __restrict__ outb) {        // h1: N x 32 (bf16x4)
    __shared__ float4 sA[32][9];
    __shared__ float4 sR[32 * 32];
    __shared__ float4 sT[32 * 32];
    __shared__ ushort_t scol[CCAP];
    int t = threadIdx.x;
    for (int i = t; i < 32 * 32; i += 256) { sR[i] = Wrel[i]; sT[i] = Wroot[i]; }
    int blk0 = blockIdx.x * 32;
    int ebeg = rowptr[blk0], eend = rowptr[blk0 + 32];
    bool gat = t < 128;
    int na = t >> 2, c = t & 3;
    int node = blk0 + (gat ? na : 0);
    int beg = gat ? rowptr[node] : 0;
    int end = gat ? rowptr[node + 1] : 0;
    float4 aLo = {0.f, 0.f, 0.f, 0.f}, aHi = {0.f, 0.f, 0.f, 0.f};
    for (int base = ebeg; base < eend; base += CCAP) {
        int cnt = eend - base < CCAP ? eend - base : CCAP;
        __syncthreads();
        for (int i = t; i < cnt; i += 256) scol[i] = col[base + i];
        __syncthreads();
        if (gat) {
            int lo = beg > base ? beg : base;
            int hi = end < base + cnt ? end : base + cnt;
            int e = lo;
            for (; e + 4 <= hi; e += 4) {
                uint4 u0 = xb4[(size_t)scol[e - base] * 4 + c];
                uint4 u1 = xb4[(size_t)scol[e - base + 1] * 4 + c];
                uint4 u2 = xb4[(size_t)scol[e - base + 2] * 4 + c];
                uint4 u3 = xb4[(size_t)scol[e - base + 3] * 4 + c];
                acc8(u0, aLo, aHi); acc8(u1, aLo, aHi);
                acc8(u2, aLo, aHi); acc8(u3, aLo, aHi);
            }
            for (; e < hi; ++e) {
                uint4 u = xb4[(size_t)scol[e - base] * 4 + c];
                acc8(u, aLo, aHi);
            }
        }
    }
    if (gat) { sA[na][2 * c] = aLo; sA[na][2 * c + 1] = aHi; }
    __syncthreads();
    // ---- Phase B: 2 nodes x 8 outputs per thread (root term in fp32) ----
    int jg = t % 16, mg = t / 16;
    int n0 = blk0 + mg * 2;
    float4 bb0 = bias[2 * jg], bb1 = bias[2 * jg + 1];
    float4 acc00 = bb0, acc01 = bb1, acc10 = bb0, acc11 = bb1;
#pragma unroll 2
    for (int kc = 0; kc < 8; ++kc) {
        float4 a0 = sA[2 * mg][kc];
        float4 a1 = sA[2 * mg + 1][kc];
        float4 x0 = x[(size_t)n0 * 8 + kc];
        float4 x1 = x[(size_t)(n0 + 1) * 8 + kc];
#pragma unroll
        for (int tt = 0; tt < 4; ++tt) {
            int k = kc * 4 + tt;
            float4 wr0 = sR[k * 32 + 2 * jg], wr1 = sR[k * 32 + 2 * jg + 1];
            float4 wt0 = sT[k * 32 + 2 * jg], wt1 = sT[k * 32 + 2 * jg + 1];
            float av0 = fcomp(a0, tt), xv0 = fcomp(x0, tt);
            float av1 = fcomp(a1, tt), xv1 = fcomp(x1, tt);
            acc00.x += av0 * wr0.x + xv0 * wt0.x;
            acc00.y += av0 * wr0.y + xv0 * wt0.y;
            acc00.z += av0 * wr0.z + xv0 * wt0.z;
            acc00.w += av0 * wr0.w + xv0 * wt0.w;
            acc01.x += av0 * wr1.x + xv0 * wt1.x;
            acc01.y += av0 * wr1.y + xv0 * wt1.y;
            acc01.z += av0 * wr1.z + xv0 * wt1.z;
            acc01.w += av0 * wr1.w + xv0 * wt1.w;
            acc10.x += av1 * wr0.x + xv1 * wt0.x;
            acc10.y += av1 * wr0.y + xv1 * wt0.y;
            acc10.z += av1 * wr0.z + xv1 * wt0.z;
            acc10.w += av1 * wr0.w + xv1 * wt0.w;
            acc11.x += av1 * wr1.x + xv1 * wt1.x;
            acc11.y += av1 * wr1.y + xv1 * wt1.y;
            acc11.z += av1 * wr1.z + xv1 * wt1.z;
            acc11.w += av1 * wr1.w + xv1 * wt1.w;
        }
    }
    float4 r;
    r.x = fmaxf(acc00.x, 0.f); r.y = fmaxf(acc00.y, 0.f);
    r.z = fmaxf(acc00.z, 0.f); r.w = fmaxf(acc00.w, 0.f);
    outb[(size_t)n0 * 32 + 2 * jg] = pack4bf(r);
    r.x = fmaxf(acc01.x, 0.f); r.y = fmaxf(acc01.y, 0.f);
    r.z = fmaxf(acc01.z, 0.f); r.w = fmaxf(acc01.w, 0.f);
    outb[(size_t)n0 * 32 + 2 * jg + 1] = pack4bf(r);
    r.x = fmaxf(acc10.x, 0.f); r.y = fmaxf(acc10.y, 0.f);
    r.z = fmaxf(acc10.z, 0.f); r.w = fmaxf(acc10.w, 0.f);
    outb[(size_t)(n0 + 1) * 32 + 2 * jg] = pack4bf(r);
    r.x = fmaxf(acc11.x, 0.f); r.y = fmaxf(acc11.y, 0.f);
    r.z = fmaxf(acc11.z, 0.f); r.w = fmaxf(acc11.w, 0.f);
    outb[(size_t)(n0 + 1) * 32 + 2 * jg + 1] = pack4bf(r);
}

// ====== L2 transform: reads h1 bf16; y2(fp8) = h1@W2rel, z2(fp32) = h1@W2root + b2 ======
__global__ __launch_bounds__(256, 6) void mmyz_kernel(
        const uint2* __restrict__ hb,      // N x 32 (bf16x4)
        const float4* __restrict__ Wrel,   // 128 x 16
        const float4* __restrict__ Wroot,  // 128 x 16
        const float4* __restrict__ bias,   // 16
        unsigned int* __restrict__ y2f8,   // N x 16 (fp8x4)
        float4* __restrict__ z2) {
    __shared__ float4 sR[32 * 16];
    __shared__ float4 sT[32 * 16];
    int jl = threadIdx.x % 16;
    int mg = threadIdx.x / 16;
    int n0 = blockIdx.x * 32 + mg * 2;
    float4 bb = bias[jl];
    float4 ay0 = {0.f, 0.f, 0.f, 0.f}, ay1 = {0.f, 0.f, 0.f, 0.f};
    float4 az0 = bb, az1 = bb;
    for (int s = 0; s < 4; ++s) {
        if (s) __syncthreads();
        for (int i = threadIdx.x; i < 512; i += 256) {
            sR[i] = Wrel[s * 512 + i];
            sT[i] = Wroot[s * 512 + i];
        }
        __syncthreads();
#pragma unroll 2
        for (int kc = 0; kc < 8; ++kc) {
            float4 h0 = unp4(hb[(size_t)n0 * 32 + s * 8 + kc]);
            float4 h1 = unp4(hb[(size_t)(n0 + 1) * 32 + s * 8 + kc]);
#pragma unroll
            for (int tt = 0; tt < 4; ++tt) {
                float4 wr = sR[(kc * 4 + tt) * 16 + jl];
                float4 wt = sT[(kc * 4 + tt) * 16 + jl];
                float v0 = fcomp(h0, tt), v1 = fcomp(h1, tt);
                ay0.x += v0 * wr.x; ay0.y += v0 * wr.y;
                ay0.z += v0 * wr.z; ay0.w += v0 * wr.w;
                az0.x += v0 * wt.x; az0.y += v0 * wt.y;
                az0.z += v0 * wt.z; az0.w += v0 * wt.w;
                ay1.x += v1 * wr.x; ay1.y += v1 * wr.y;
                ay1.z += v1 * wr.z; ay1.w += v1 * wr.w;
                az1.x += v1 * wt.x; az1.y += v1 * wt.y;
                az1.z += v1 * wt.z; az1.w += v1 * wt.w;
            }
        }
    }
    y2f8[(size_t)n0 * 16 + jl] = pack4fp8(ay0);
    z2[(size_t)n0 * 16 + jl] = az0;
    y2f8[(size_t)(n0 + 1) * 16 + jl] = pack4fp8(ay1);
    z2[(size_t)(n0 + 1) * 16 + jl] = az1;
}

// ====== fused L3: gather y2 (uint2 = 8 fp8) + relu(z2+agg) + transform 64->32 ======
__global__ __launch_bounds__(256, 5) void fconv3_kernel(
        const uint2* __restrict__ yf8,     // y2: N x 8 (fp8x8)
        const float4* __restrict__ z,      // z2: N x 16
        const int* __restrict__ rowptr,
        const ushort_t* __restrict__ col,
        const float4* __restrict__ Wrel,   // 64 x 8
        const float4* __restrict__ Wroot,  // 64 x 8
        const float4* __restrict__ bias,   // 8
        uint2* __restrict__ y3b,           // N x 8 (bf16x4)
        float4* __restrict__ z3) {
    __shared__ float4 sH[32][17];
    __shared__ float4 sR[64 * 8];
    __shared__ float4 sT[64 * 8];
    __shared__ ushort_t scol[CCAP];
    int t = threadIdx.x;
    for (int i = t; i < 64 * 8; i += 256) { sR[i] = Wrel[i]; sT[i] = Wroot[i]; }
    int blk0 = blockIdx.x * 32;
    int ebeg = rowptr[blk0], eend = rowptr[blk0 + 32];
    int na = t >> 3, c = t & 7;
    int node = blk0 + na;
    int beg = rowptr[node], end = rowptr[node + 1];
    float4 aLo = z[(size_t)node * 16 + 2 * c];
    float4 aHi = z[(size_t)node * 16 + 2 * c + 1];
    for (int base = ebeg; base < eend; base += CCAP) {
        int cnt = eend - base < CCAP ? eend - base : CCAP;
        __syncthreads();
        for (int i = t; i < cnt; i += 256) scol[i] = col[base + i];
        __syncthreads();
        int lo = beg > base ? beg : base;
        int hi = end < base + cnt ? end : base + cnt;
        int e = lo;
        for (; e + 4 <= hi; e += 4) {
            uint2 u0 = yf8[(size_t)scol[e - base] * 8 + c];
            uint2 u1 = yf8[(size_t)scol[e - base + 1] * 8 + c];
            uint2 u2 = yf8[(size_t)scol[e - base + 2] * 8 + c];
            uint2 u3 = yf8[(size_t)scol[e - base + 3] * 8 + c];
            accf8x4(u0.x, aLo); accf8x4(u0.y, aHi);
            accf8x4(u1.x, aLo); accf8x4(u1.y, aHi);
            accf8x4(u2.x, aLo); accf8x4(u2.y, aHi);
            accf8x4(u3.x, aLo); accf8x4(u3.y, aHi);
        }
        for (; e < hi; ++e) {
            uint2 u = yf8[(size_t)scol[e - base] * 8 + c];
            accf8x4(u.x, aLo); accf8x4(u.y, aHi);
        }
    }
    aLo.x = fmaxf(aLo.x, 0.f); aLo.y = fmaxf(aLo.y, 0.f);
    aLo.z = fmaxf(aLo.z, 0.f); aLo.w = fmaxf(aLo.w, 0.f);
    aHi.x = fmaxf(aHi.x, 0.f); aHi.y = fmaxf(aHi.y, 0.f);
    aHi.z = fmaxf(aHi.z, 0.f); aHi.w = fmaxf(aHi.w, 0.f);
    sH[na][2 * c] = aLo;
    sH[na][2 * c + 1] = aHi;
    __syncthreads();
    // ---- Phase B: 1 node x 4 outputs per thread ----
    int jl = t & 7, mg = t >> 3;
    int nodeB = blk0 + mg;
    float4 ay = {0.f, 0.f, 0.f, 0.f};
    float4 az = bias[jl];
#pragma unroll 4
    for (int kc = 0; kc < 16; ++kc) {
        float4 h4 = sH[mg][kc];
#pragma unroll
        for (int tt = 0; tt < 4; ++tt) {
            float hv = fcomp(h4, tt);
            float4 wr = sR[(kc * 4 + tt) * 8 + jl];
            float4 wt = sT[(kc * 4 + tt) * 8 + jl];
            ay.x += hv * wr.x; ay.y += hv * wr.y;
            ay.z += hv * wr.z; ay.w += hv * wr.w;
            az.x += hv * wt.x; az.y += hv * wt.y;
            az.z += hv * wt.z; az.w += hv * wt.w;
        }
    }
    y3b[(size_t)nodeB * 8 + jl] = pack4bf(ay);
    z3[(size_t)nodeB * 8 + jl] = az;
}

// ====== fused L4: gather y3 (uint4-wide bf16) + relu(z3+agg) + folded dot ======
__global__ __launch_bounds__(256, 8) void fconv4_kernel(
        const uint4* __restrict__ yb4,     // y3: N x 4 (bf16x8)
        const float4* __restrict__ z,      // z3: N x 8
        const int* __restrict__ rowptr,
        const ushort_t* __restrict__ col,
        const float* __restrict__ wf,      // 65
        float* __restrict__ y4,
        float* __restrict__ z4) {
    __shared__ float4 sH[32][9];
    __shared__ float4 sF[8], sRF[8];
    __shared__ float sB;
    __shared__ ushort_t scol[CCAP];
    int t = threadIdx.x;
    if (t < 8) sF[t] = ((const float4*)wf)[t];
    else if (t < 16) sRF[t - 8] = ((const float4*)wf)[t];
    else if (t == 16) sB = wf[64];
    int blk0 = blockIdx.x * 32;
    int ebeg = rowptr[blk0], eend = rowptr[blk0 + 32];
    bool gat = t < 128;
    int na = t >> 2, c = t & 3;
    int node = blk0 + (gat ? na : 0);
    int beg = gat ? rowptr[node] : 0;
    int end = gat ? rowptr[node + 1] : 0;
    float4 aLo = {0.f, 0.f, 0.f, 0.f}, aHi = {0.f, 0.f, 0.f, 0.f};
    if (gat) {
        aLo = z[(size_t)node * 8 + 2 * c];
        aHi = z[(size_t)node * 8 + 2 * c + 1];
    }
    for (int base = ebeg; base < eend; base += CCAP) {
        int cnt = eend - base < CCAP ? eend - base : CCAP;
        __syncthreads();
        for (int i = t; i < cnt; i += 256) scol[i] = col[base + i];
        __syncthreads();
        if (gat) {
            int lo = beg > base ? beg : base;
            int hi = end < base + cnt ? end : base + cnt;
            int e = lo;
            for (; e + 4 <= hi; e += 4) {
                uint4 u0 = yb4[(size_t)scol[e - base] * 4 + c];
                uint4 u1 = yb4[(size_t)scol[e - base + 1] * 4 + c];
                uint4 u2 = yb4[(size_t)scol[e - base + 2] * 4 + c];
                uint4 u3 = yb4[(size_t)scol[e - base + 3] * 4 + c];
                acc8(u0, aLo, aHi); acc8(u1, aLo, aHi);
                acc8(u2, aLo, aHi); acc8(u3, aLo, aHi);
            }
            for (; e < hi; ++e) {
                uint4 u = yb4[(size_t)scol[e - base] * 4 + c];
                acc8(u, aLo, aHi);
            }
        }
    }
    if (gat) {
        aLo.x = fmaxf(aLo.x, 0.f); aLo.y = fmaxf(aLo.y, 0.f);
        aLo.z = fmaxf(aLo.z, 0.f); aLo.w = fmaxf(aLo.w, 0.f);
        aHi.x = fmaxf(aHi.x, 0.f); aHi.y = fmaxf(aHi.y, 0.f);
        aHi.z = fmaxf(aHi.z, 0.f); aHi.w = fmaxf(aHi.w, 0.f);
        sH[na][2 * c] = aLo;
        sH[na][2 * c + 1] = aHi;
    }
    __syncthreads();
    if (t < 32) {
        int nd = blk0 + t;
        float ay = 0.f, az = 0.f;
#pragma unroll
        for (int kc = 0; kc < 8; ++kc) {
            float4 h4 = sH[t][kc];
            float4 f = sF[kc], r = sRF[kc];
            ay += h4.x * f.x + h4.y * f.y + h4.z * f.z + h4.w * f.w;
            az += h4.x * r.x + h4.y * r.y + h4.z * r.z + h4.w * r.w;
        }
        y4[nd] = ay;
        z4[nd] = az + sB;
    }
}

// ====== gather + pool + last-block finalize ======
__global__ __launch_bounds__(256) void gpool_final_kernel(
        const float* __restrict__ y4,
        const float* __restrict__ z4,
        const int* __restrict__ rowptr,
        const ushort_t* __restrict__ col,
        const int* __restrict__ batch,
        float* __restrict__ sums,
        float* __restrict__ counts,
        int* __restrict__ ctr,
        const float* __restrict__ bfc,
        float* __restrict__ out) {
    __shared__ float ls[NG];
    __shared__ float lc[NG];
    __shared__ int sDone;
    if (threadIdx.x < NG) { ls[threadIdx.x] = 0.f; lc[threadIdx.x] = 0.f; }
    if (threadIdx.x == 0) sDone = 0;
    __syncthreads();
    int nd = blockIdx.x * 256 + threadIdx.x;
    if (nd < NN) {
        float v = z4[nd];
        int beg = rowptr[nd], end = rowptr[nd + 1];
        int e = beg;
        for (; e + 4 <= end; e += 4) {
            v += (y4[col[e]] + y4[col[e + 1]]) + (y4[col[e + 2]] + y4[col[e + 3]]);
        }
        for (; e < end; ++e) v += y4[col[e]];
        int g = batch[nd];
        atomicAdd(&ls[g], v);
        atomicAdd(&lc[g], 1.f);
    }
    __syncthreads();
    if (threadIdx.x < NG && lc[threadIdx.x] > 0.f) {
        atomicAdd(&sums[threadIdx.x], ls[threadIdx.x]);
        atomicAdd(&counts[threadIdx.x], lc[threadIdx.x]);
    }
    __threadfence();
    __syncthreads();
    if (threadIdx.x == 0) {
        if (atomicAdd(ctr, 1) == (int)gridDim.x - 1) sDone = 1;
    }
    __syncthreads();
    if (sDone && threadIdx.x < NG) {
        float s = atomicAdd(&sums[threadIdx.x], 0.f);   // coherent read
        float c = atomicAdd(&counts[threadIdx.x], 0.f);
        c = fmaxf(c, 1.0f);
        out[threadIdx.x] = s / c + bfc[0];
    }
}

extern "C" void kernel_launch(void* const* d_in, const int* in_sizes, int n_in,
                              void* d_out, int out_size, void* d_ws, size_t ws_size,
                              hipStream_t stream) {
    const float* x       = (const float*)d_in[0];
    const int*   ei      = (const int*)d_in[1];
    const int*   batch   = (const int*)d_in[2];
    const float* W1_rel  = (const float*)d_in[3];
    const float* b1      = (const float*)d_in[4];
    const float* W1_root = (const float*)d_in[5];
    const float* W2_rel  = (const float*)d_in[6];
    const float* b2      = (const float*)d_in[7];
    const float* W2_root = (const float*)d_in[8];
    const float* W3_rel  = (const float*)d_in[9];
    const float* b3      = (const float*)d_in[10];
    const float* W3_root = (const float*)d_in[11];
    const float* W4_rel  = (const float*)d_in[12];
    const float* b4      = (const float*)d_in[13];
    const float* W4_root = (const float*)d_in[14];
    const float* Wfc     = (const float*)d_in[15];
    const float* bfc     = (const float*)d_in[16];
    float* out = (float*)d_out;

    const int* src = ei;        // edge_index[0]
    const int* dst = ei + NE;   // edge_index[1]

    // workspace layout
    uint2* h1b     = (uint2*)d_ws;                   // N x 32 (bf16 h1)
    float* bufZ    = (float*)(h1b + (size_t)NN * 32);// N x 64   (z2, fp32)
    float* z3      = bufZ + (size_t)NN * 64;         // N x 32   (fp32)
    float* y4      = z3 + (size_t)NN * 32;           // N
    float* z4      = y4 + NN;                        // N
    float* wf      = z4 + NN;                        // 65 (pad 68)
    int*   deg     = (int*)(wf + 68);                // N       -- zero block start
    float* sums    = (float*)(deg + NN);             // G
    float* counts  = sums + NG;                      // G
    int*   ctr     = (int*)(counts + NG);            // 1
    int*   sc      = ctr + 1;                        // 2       -- zero block end
    int*   rowptr  = sc + 2;                         // N+1
    int*   epos    = rowptr + NN + 1;                // E
    int*   bsum    = epos + NE;                      // SCAN_NB (pad 160)
    ushort_t* colu = (ushort_t*)(bsum + 160);        // E (2B)
    unsigned long long pa = (unsigned long long)(colu + NE);
    pa = (pa + 15ull) & ~15ull;
    uint2* xb      = (uint2*)pa;                     // N x 8  (bf16 x)
    unsigned int* y2f8 = (unsigned int*)(xb + (size_t)NN * 8);  // N x 16 (fp8 y2)
    uint2* y3b     = (uint2*)(y2f8 + (size_t)NN * 16);          // N x 8 (bf16 y3)

    const int NZ = NN + 2 * NG + 3;   // deg + sums + counts + ctr + sc[2]

    // ---- zero scratch ----
    zero_kernel<<<(NZ + 255) / 256, 256, 0, stream>>>(deg, NZ);

    // ---- csr1: hist + x->bf16 + fold ----
    csr1_kernel<<<(NE + 255) / 256, 256, 0, stream>>>(
        dst, deg, epos, (const float4*)x, xb, W4_rel, W4_root, b4, Wfc, wf);

    // ---- csr2: scan + scan-offset + fill (2 device-wide syncs, 157 resident blocks) ----
    csr2_kernel<<<SCAN_NB, 256, 0, stream>>>(
        deg, rowptr, bsum, src, dst, epos, colu, sc);

    // ---- Layer 1 fused: gather(xb) + conv 32->128 -> h1 bf16 ----
    fconv1_kernel<<<NN / 32, 256, 0, stream>>>(
        (const uint4*)xb, (const float4*)x, rowptr, colu,
        (const float4*)W1_rel, (const float4*)W1_root, (const float4*)b1,
        h1b);

    // ---- Layer 2 transform: h1(bf16) -> y2(fp8), z2(fp32) ----
    mmyz_kernel<<<NN / 32, 256, 0, stream>>>(
        h1b, (const float4*)W2_rel, (const float4*)W2_root,
        (const float4*)b2, y2f8, (float4*)bufZ);

    // ---- Layer 3 fused: gather(y2 fp8) + relu(z2+agg) + transform 64->32 ----
    fconv3_kernel<<<NN / 32, 256, 0, stream>>>(
        (const uint2*)y2f8, (const float4*)bufZ, rowptr, colu,
        (const float4*)W3_rel, (const float4*)W3_root, (const float4*)b3,
        y3b, (float4*)z3);

    // ---- Layer 4 fused: gather(y3 bf16) + relu(z3+agg) + folded dot ----
    fconv4_kernel<<<NN / 32, 256, 0, stream>>>(
        (const uint4*)y3b, (const float4*)z3, rowptr, colu, wf, y4, z4);

    // ---- final gather + pool + FC (last block finalizes) ----
    gpool_final_kernel<<<(NN + 255) / 256, 256, 0, stream>>>(
        y4, z4, rowptr, colu, batch, sums, counts, ctr, bfc, out);
}

// Round 20
// 139.109 us; speedup vs baseline: 1.1519x; 1.1519x over previous
//
#include <hip/hip_runtime.h>

#define NN 40000
#define NE 640000
#define NG 64
#define SCAN_NB ((NN + 255) / 256)   // 157 blocks
#define CCAP 768                     // LDS col-staging chunk

typedef unsigned short ushort_t;

__device__ __forceinline__ float fcomp(const float4& v, int t) {
    return t == 0 ? v.x : t == 1 ? v.y : t == 2 ? v.z : v.w;
}
// ---- bf16 pack/unpack (RNE) ----
__device__ __forceinline__ unsigned int pack2bf(float a, float b) {
    unsigned int ua = __float_as_uint(a);
    unsigned int ub = __float_as_uint(b);
    ua = (ua + 0x7fffu + ((ua >> 16) & 1u)) >> 16;
    ub = (ub + 0x7fffu + ((ub >> 16) & 1u)) >> 16;
    return ua | (ub << 16);
}
__device__ __forceinline__ uint2 pack4bf(const float4& v) {
    return make_uint2(pack2bf(v.x, v.y), pack2bf(v.z, v.w));
}
__device__ __forceinline__ float lo2f(unsigned int u) { return __uint_as_float(u << 16); }
__device__ __forceinline__ float hi2f(unsigned int u) { return __uint_as_float(u & 0xffff0000u); }
__device__ __forceinline__ float4 unp4(const uint2& u) {
    float4 r; r.x = lo2f(u.x); r.y = hi2f(u.x); r.z = lo2f(u.y); r.w = hi2f(u.y); return r;
}
// accumulate 8 bf16 (one uint4) into two float4s
__device__ __forceinline__ void acc8(const uint4& u, float4& lo, float4& hi) {
    lo.x += lo2f(u.x); lo.y += hi2f(u.x); lo.z += lo2f(u.y); lo.w += hi2f(u.y);
    hi.x += lo2f(u.z); hi.y += hi2f(u.z); hi.z += lo2f(u.w); hi.w += hi2f(u.w);
}
// ---- fp8 e4m3 (HW converts; OCP on gfx950) ----
typedef __attribute__((ext_vector_type(2))) float f32x2;
__device__ __forceinline__ unsigned int pack4fp8(const float4& v) {
    unsigned int r = 0;
    r = __builtin_amdgcn_cvt_pk_fp8_f32(v.x, v.y, r, false);
    r = __builtin_amdgcn_cvt_pk_fp8_f32(v.z, v.w, r, true);
    return r;
}
__device__ __forceinline__ void accf8x4(unsigned int u, float4& a) {
    f32x2 lo = __builtin_amdgcn_cvt_pk_f32_fp8(u, false);
    f32x2 hi = __builtin_amdgcn_cvt_pk_f32_fp8(u, true);
    a.x += lo[0]; a.y += lo[1]; a.z += hi[0]; a.w += hi[1];
}

// ===== prep: zero deg+sums+counts+ctr, convert x -> bf16, fold Wfc into L4 =====
__global__ __launch_bounds__(256) void prep_kernel(
        int* __restrict__ zp, int nz,
        const float4* __restrict__ x4,
        uint2* __restrict__ xb,
        const float* __restrict__ W4rel,
        const float* __restrict__ W4root,
        const float* __restrict__ b4,
        const float* __restrict__ Wfc,
        float* __restrict__ wf) {
    int i = blockIdx.x * 256 + threadIdx.x;
    if (i < nz) zp[i] = 0;
    if (i < NN * 8) { float4 v = x4[i]; xb[i] = pack4bf(v); }
    if (blockIdx.x == 0) {
        int t = threadIdx.x;
        if (t < 32) {
            float a = 0.f, b = 0.f;
#pragma unroll
            for (int j = 0; j < 16; ++j) {
                float w = Wfc[j];
                a += W4rel[t * 16 + j] * w;
                b += W4root[t * 16 + j] * w;
            }
            wf[t] = a;
            wf[32 + t] = b;
        } else if (t == 32) {
            float s = 0.f;
#pragma unroll
            for (int j = 0; j < 16; ++j) s += b4[j] * Wfc[j];
            wf[64] = s;
        }
    }
}

// ================= CSR build =================
__global__ void hist_kernel(const int* __restrict__ dst, int* __restrict__ deg,
                            int* __restrict__ epos) {
    int e = blockIdx.x * blockDim.x + threadIdx.x;
    if (e < NE) epos[e] = atomicAdd(&deg[dst[e]], 1);
}

__global__ __launch_bounds__(256) void scan1_kernel(const int* __restrict__ deg,
                                                    int* __restrict__ rowptr,
                                                    int* __restrict__ bsum) {
    __shared__ int ws[4];
    __shared__ int wpre[4];
    int i = blockIdx.x * 256 + threadIdx.x;
    int lane = threadIdx.x & 63, wid = threadIdx.x >> 6;
    int v = (i < NN) ? deg[i] : 0;
    int incl = v;
#pragma unroll
    for (int off = 1; off < 64; off <<= 1) {
        int u = __shfl_up(incl, off, 64);
        if (lane >= off) incl += u;
    }
    if (lane == 63) ws[wid] = incl;
    __syncthreads();
    if (threadIdx.x == 0) {
        int s = 0;
#pragma unroll
        for (int w = 0; w < 4; ++w) { wpre[w] = s; s += ws[w]; }
        bsum[blockIdx.x] = s;
    }
    __syncthreads();
    if (i < NN) rowptr[i] = wpre[wid] + (incl - v);
}

// merged scan2+scan3
__global__ __launch_bounds__(256) void scan23_kernel(int* __restrict__ rowptr,
                                                     const int* __restrict__ bsum) {
    __shared__ int ws[4];
    int t = threadIdx.x, b = blockIdx.x;
    int v = (t < b) ? bsum[t] : 0;
#pragma unroll
    for (int off = 32; off; off >>= 1) v += __shfl_xor(v, off, 64);
    if ((t & 63) == 0) ws[t >> 6] = v;
    __syncthreads();
    int soff = ws[0] + ws[1] + ws[2] + ws[3];
    int i = b * 256 + t;
    if (i < NN) rowptr[i] += soff;
    if (b == SCAN_NB - 1 && t == 0) rowptr[NN] = soff + bsum[b];
}

__global__ void fill_kernel(const int* __restrict__ src, const int* __restrict__ dst,
                            const int* __restrict__ rowptr, const int* __restrict__ epos,
                            ushort_t* __restrict__ col) {
    int e = blockIdx.x * blockDim.x + threadIdx.x;
    if (e < NE) col[rowptr[dst[e]] + epos[e]] = (ushort_t)src[e];
}

// ====== fused L1: gather xb (uint4-wide bf16) + conv 32->128, h1 out bf16 ======
__global__ __launch_bounds__(256, 4) void fconv1_kernel(
        const uint4* __restrict__ xb4,     // N x 4 (bf16x8)
        const float4* __restrict__ x,      // N x 8 (fp32, root term)
        const int* __restrict__ rowptr,
        const ushort_t* __restrict__ col,
        const float4* __restrict__ Wrel,
        const float4* __restrict__ Wroot,
        const float4* __restrict__ bias,
        uint2* __restrict__ outb) {        // h1: N x 32 (bf16x4)
    __shared__ float4 sA[32][9];
    __shared__ float4 sR[32 * 32];
    __shared__ float4 sT[32 * 32];
    __shared__ ushort_t scol[CCAP];
    int t = threadIdx.x;
    for (int i = t; i < 32 * 32; i += 256) { sR[i] = Wrel[i]; sT[i] = Wroot[i]; }
    int blk0 = blockIdx.x * 32;
    int ebeg = rowptr[blk0], eend = rowptr[blk0 + 32];
    bool gat = t < 128;
    int na = t >> 2, c = t & 3;
    int node = blk0 + (gat ? na : 0);
    int beg = gat ? rowptr[node] : 0;
    int end = gat ? rowptr[node + 1] : 0;
    float4 aLo = {0.f, 0.f, 0.f, 0.f}, aHi = {0.f, 0.f, 0.f, 0.f};
    for (int base = ebeg; base < eend; base += CCAP) {
        int cnt = eend - base < CCAP ? eend - base : CCAP;
        __syncthreads();
        for (int i = t; i < cnt; i += 256) scol[i] = col[base + i];
        __syncthreads();
        if (gat) {
            int lo = beg > base ? beg : base;
            int hi = end < base + cnt ? end : base + cnt;
            int e = lo;
            for (; e + 4 <= hi; e += 4) {
                uint4 u0 = xb4[(size_t)scol[e - base] * 4 + c];
                uint4 u1 = xb4[(size_t)scol[e - base + 1] * 4 + c];
                uint4 u2 = xb4[(size_t)scol[e - base + 2] * 4 + c];
                uint4 u3 = xb4[(size_t)scol[e - base + 3] * 4 + c];
                acc8(u0, aLo, aHi); acc8(u1, aLo, aHi);
                acc8(u2, aLo, aHi); acc8(u3, aLo, aHi);
            }
            for (; e < hi; ++e) {
                uint4 u = xb4[(size_t)scol[e - base] * 4 + c];
                acc8(u, aLo, aHi);
            }
        }
    }
    if (gat) { sA[na][2 * c] = aLo; sA[na][2 * c + 1] = aHi; }
    __syncthreads();
    // ---- Phase B: 2 nodes x 8 outputs per thread (root term in fp32) ----
    int jg = t % 16, mg = t / 16;
    int n0 = blk0 + mg * 2;
    float4 bb0 = bias[2 * jg], bb1 = bias[2 * jg + 1];
    float4 acc00 = bb0, acc01 = bb1, acc10 = bb0, acc11 = bb1;
#pragma unroll 2
    for (int kc = 0; kc < 8; ++kc) {
        float4 a0 = sA[2 * mg][kc];
        float4 a1 = sA[2 * mg + 1][kc];
        float4 x0 = x[(size_t)n0 * 8 + kc];
        float4 x1 = x[(size_t)(n0 + 1) * 8 + kc];
#pragma unroll
        for (int tt = 0; tt < 4; ++tt) {
            int k = kc * 4 + tt;
            float4 wr0 = sR[k * 32 + 2 * jg], wr1 = sR[k * 32 + 2 * jg + 1];
            float4 wt0 = sT[k * 32 + 2 * jg], wt1 = sT[k * 32 + 2 * jg + 1];
            float av0 = fcomp(a0, tt), xv0 = fcomp(x0, tt);
            float av1 = fcomp(a1, tt), xv1 = fcomp(x1, tt);
            acc00.x += av0 * wr0.x + xv0 * wt0.x;
            acc00.y += av0 * wr0.y + xv0 * wt0.y;
            acc00.z += av0 * wr0.z + xv0 * wt0.z;
            acc00.w += av0 * wr0.w + xv0 * wt0.w;
            acc01.x += av0 * wr1.x + xv0 * wt1.x;
            acc01.y += av0 * wr1.y + xv0 * wt1.y;
            acc01.z += av0 * wr1.z + xv0 * wt1.z;
            acc01.w += av0 * wr1.w + xv0 * wt1.w;
            acc10.x += av1 * wr0.x + xv1 * wt0.x;
            acc10.y += av1 * wr0.y + xv1 * wt0.y;
            acc10.z += av1 * wr0.z + xv1 * wt0.z;
            acc10.w += av1 * wr0.w + xv1 * wt0.w;
            acc11.x += av1 * wr1.x + xv1 * wt1.x;
            acc11.y += av1 * wr1.y + xv1 * wt1.y;
            acc11.z += av1 * wr1.z + xv1 * wt1.z;
            acc11.w += av1 * wr1.w + xv1 * wt1.w;
        }
    }
    float4 r;
    r.x = fmaxf(acc00.x, 0.f); r.y = fmaxf(acc00.y, 0.f);
    r.z = fmaxf(acc00.z, 0.f); r.w = fmaxf(acc00.w, 0.f);
    outb[(size_t)n0 * 32 + 2 * jg] = pack4bf(r);
    r.x = fmaxf(acc01.x, 0.f); r.y = fmaxf(acc01.y, 0.f);
    r.z = fmaxf(acc01.z, 0.f); r.w = fmaxf(acc01.w, 0.f);
    outb[(size_t)n0 * 32 + 2 * jg + 1] = pack4bf(r);
    r.x = fmaxf(acc10.x, 0.f); r.y = fmaxf(acc10.y, 0.f);
    r.z = fmaxf(acc10.z, 0.f); r.w = fmaxf(acc10.w, 0.f);
    outb[(size_t)(n0 + 1) * 32 + 2 * jg] = pack4bf(r);
    r.x = fmaxf(acc11.x, 0.f); r.y = fmaxf(acc11.y, 0.f);
    r.z = fmaxf(acc11.z, 0.f); r.w = fmaxf(acc11.w, 0.f);
    outb[(size_t)(n0 + 1) * 32 + 2 * jg + 1] = pack4bf(r);
}

// ====== L2 transform: reads h1 bf16; y2(fp8) = h1@W2rel, z2(fp32) = h1@W2root + b2 ======
__global__ __launch_bounds__(256, 6) void mmyz_kernel(
        const uint2* __restrict__ hb,      // N x 32 (bf16x4)
        const float4* __restrict__ Wrel,   // 128 x 16
        const float4* __restrict__ Wroot,  // 128 x 16
        const float4* __restrict__ bias,   // 16
        unsigned int* __restrict__ y2f8,   // N x 16 (fp8x4)
        float4* __restrict__ z2) {
    __shared__ float4 sR[32 * 16];
    __shared__ float4 sT[32 * 16];
    int jl = threadIdx.x % 16;
    int mg = threadIdx.x / 16;
    int n0 = blockIdx.x * 32 + mg * 2;
    float4 bb = bias[jl];
    float4 ay0 = {0.f, 0.f, 0.f, 0.f}, ay1 = {0.f, 0.f, 0.f, 0.f};
    float4 az0 = bb, az1 = bb;
    for (int s = 0; s < 4; ++s) {
        if (s) __syncthreads();
        for (int i = threadIdx.x; i < 512; i += 256) {
            sR[i] = Wrel[s * 512 + i];
            sT[i] = Wroot[s * 512 + i];
        }
        __syncthreads();
#pragma unroll 2
        for (int kc = 0; kc < 8; ++kc) {
            float4 h0 = unp4(hb[(size_t)n0 * 32 + s * 8 + kc]);
            float4 h1 = unp4(hb[(size_t)(n0 + 1) * 32 + s * 8 + kc]);
#pragma unroll
            for (int tt = 0; tt < 4; ++tt) {
                float4 wr = sR[(kc * 4 + tt) * 16 + jl];
                float4 wt = sT[(kc * 4 + tt) * 16 + jl];
                float v0 = fcomp(h0, tt), v1 = fcomp(h1, tt);
                ay0.x += v0 * wr.x; ay0.y += v0 * wr.y;
                ay0.z += v0 * wr.z; ay0.w += v0 * wr.w;
                az0.x += v0 * wt.x; az0.y += v0 * wt.y;
                az0.z += v0 * wt.z; az0.w += v0 * wt.w;
                ay1.x += v1 * wr.x; ay1.y += v1 * wr.y;
                ay1.z += v1 * wr.z; ay1.w += v1 * wr.w;
                az1.x += v1 * wt.x; az1.y += v1 * wt.y;
                az1.z += v1 * wt.z; az1.w += v1 * wt.w;
            }
        }
    }
    y2f8[(size_t)n0 * 16 + jl] = pack4fp8(ay0);
    z2[(size_t)n0 * 16 + jl] = az0;
    y2f8[(size_t)(n0 + 1) * 16 + jl] = pack4fp8(ay1);
    z2[(size_t)(n0 + 1) * 16 + jl] = az1;
}

// ====== fused L3: gather y2 (uint2 = 8 fp8) + relu(z2+agg) + transform 64->32 ======
__global__ __launch_bounds__(256, 5) void fconv3_kernel(
        const uint2* __restrict__ yf8,     // y2: N x 8 (fp8x8)
        const float4* __restrict__ z,      // z2: N x 16
        const int* __restrict__ rowptr,
        const ushort_t* __restrict__ col,
        const float4* __restrict__ Wrel,   // 64 x 8
        const float4* __restrict__ Wroot,  // 64 x 8
        const float4* __restrict__ bias,   // 8
        uint2* __restrict__ y3b,           // N x 8 (bf16x4)
        float4* __restrict__ z3) {
    __shared__ float4 sH[32][17];
    __shared__ float4 sR[64 * 8];
    __shared__ float4 sT[64 * 8];
    __shared__ ushort_t scol[CCAP];
    int t = threadIdx.x;
    for (int i = t; i < 64 * 8; i += 256) { sR[i] = Wrel[i]; sT[i] = Wroot[i]; }
    int blk0 = blockIdx.x * 32;
    int ebeg = rowptr[blk0], eend = rowptr[blk0 + 32];
    int na = t >> 3, c = t & 7;
    int node = blk0 + na;
    int beg = rowptr[node], end = rowptr[node + 1];
    float4 aLo = z[(size_t)node * 16 + 2 * c];
    float4 aHi = z[(size_t)node * 16 + 2 * c + 1];
    for (int base = ebeg; base < eend; base += CCAP) {
        int cnt = eend - base < CCAP ? eend - base : CCAP;
        __syncthreads();
        for (int i = t; i < cnt; i += 256) scol[i] = col[base + i];
        __syncthreads();
        int lo = beg > base ? beg : base;
        int hi = end < base + cnt ? end : base + cnt;
        int e = lo;
        for (; e + 4 <= hi; e += 4) {
            uint2 u0 = yf8[(size_t)scol[e - base] * 8 + c];
            uint2 u1 = yf8[(size_t)scol[e - base + 1] * 8 + c];
            uint2 u2 = yf8[(size_t)scol[e - base + 2] * 8 + c];
            uint2 u3 = yf8[(size_t)scol[e - base + 3] * 8 + c];
            accf8x4(u0.x, aLo); accf8x4(u0.y, aHi);
            accf8x4(u1.x, aLo); accf8x4(u1.y, aHi);
            accf8x4(u2.x, aLo); accf8x4(u2.y, aHi);
            accf8x4(u3.x, aLo); accf8x4(u3.y, aHi);
        }
        for (; e < hi; ++e) {
            uint2 u = yf8[(size_t)scol[e - base] * 8 + c];
            accf8x4(u.x, aLo); accf8x4(u.y, aHi);
        }
    }
    aLo.x = fmaxf(aLo.x, 0.f); aLo.y = fmaxf(aLo.y, 0.f);
    aLo.z = fmaxf(aLo.z, 0.f); aLo.w = fmaxf(aLo.w, 0.f);
    aHi.x = fmaxf(aHi.x, 0.f); aHi.y = fmaxf(aHi.y, 0.f);
    aHi.z = fmaxf(aHi.z, 0.f); aHi.w = fmaxf(aHi.w, 0.f);
    sH[na][2 * c] = aLo;
    sH[na][2 * c + 1] = aHi;
    __syncthreads();
    // ---- Phase B: 1 node x 4 outputs per thread ----
    int jl = t & 7, mg = t >> 3;
    int nodeB = blk0 + mg;
    float4 ay = {0.f, 0.f, 0.f, 0.f};
    float4 az = bias[jl];
#pragma unroll 4
    for (int kc = 0; kc < 16; ++kc) {
        float4 h4 = sH[mg][kc];
#pragma unroll
        for (int tt = 0; tt < 4; ++tt) {
            float hv = fcomp(h4, tt);
            float4 wr = sR[(kc * 4 + tt) * 8 + jl];
            float4 wt = sT[(kc * 4 + tt) * 8 + jl];
            ay.x += hv * wr.x; ay.y += hv * wr.y;
            ay.z += hv * wr.z; ay.w += hv * wr.w;
            az.x += hv * wt.x; az.y += hv * wt.y;
            az.z += hv * wt.z; az.w += hv * wt.w;
        }
    }
    y3b[(size_t)nodeB * 8 + jl] = pack4bf(ay);
    z3[(size_t)nodeB * 8 + jl] = az;
}

// ====== fused L4: gather y3 (uint4-wide bf16) + relu(z3+agg) + folded dot ======
__global__ __launch_bounds__(256, 8) void fconv4_kernel(
        const uint4* __restrict__ yb4,     // y3: N x 4 (bf16x8)
        const float4* __restrict__ z,      // z3: N x 8
        const int* __restrict__ rowptr,
        const ushort_t* __restrict__ col,
        const float* __restrict__ wf,      // 65
        float* __restrict__ y4,
        float* __restrict__ z4) {
    __shared__ float4 sH[32][9];
    __shared__ float4 sF[8], sRF[8];
    __shared__ float sB;
    __shared__ ushort_t scol[CCAP];
    int t = threadIdx.x;
    if (t < 8) sF[t] = ((const float4*)wf)[t];
    else if (t < 16) sRF[t - 8] = ((const float4*)wf)[t];
    else if (t == 16) sB = wf[64];
    int blk0 = blockIdx.x * 32;
    int ebeg = rowptr[blk0], eend = rowptr[blk0 + 32];
    bool gat = t < 128;
    int na = t >> 2, c = t & 3;
    int node = blk0 + (gat ? na : 0);
    int beg = gat ? rowptr[node] : 0;
    int end = gat ? rowptr[node + 1] : 0;
    float4 aLo = {0.f, 0.f, 0.f, 0.f}, aHi = {0.f, 0.f, 0.f, 0.f};
    if (gat) {
        aLo = z[(size_t)node * 8 + 2 * c];
        aHi = z[(size_t)node * 8 + 2 * c + 1];
    }
    for (int base = ebeg; base < eend; base += CCAP) {
        int cnt = eend - base < CCAP ? eend - base : CCAP;
        __syncthreads();
        for (int i = t; i < cnt; i += 256) scol[i] = col[base + i];
        __syncthreads();
        if (gat) {
            int lo = beg > base ? beg : base;
            int hi = end < base + cnt ? end : base + cnt;
            int e = lo;
            for (; e + 4 <= hi; e += 4) {
                uint4 u0 = yb4[(size_t)scol[e - base] * 4 + c];
                uint4 u1 = yb4[(size_t)scol[e - base + 1] * 4 + c];
                uint4 u2 = yb4[(size_t)scol[e - base + 2] * 4 + c];
                uint4 u3 = yb4[(size_t)scol[e - base + 3] * 4 + c];
                acc8(u0, aLo, aHi); acc8(u1, aLo, aHi);
                acc8(u2, aLo, aHi); acc8(u3, aLo, aHi);
            }
            for (; e < hi; ++e) {
                uint4 u = yb4[(size_t)scol[e - base] * 4 + c];
                acc8(u, aLo, aHi);
            }
        }
    }
    if (gat) {
        aLo.x = fmaxf(aLo.x, 0.f); aLo.y = fmaxf(aLo.y, 0.f);
        aLo.z = fmaxf(aLo.z, 0.f); aLo.w = fmaxf(aLo.w, 0.f);
        aHi.x = fmaxf(aHi.x, 0.f); aHi.y = fmaxf(aHi.y, 0.f);
        aHi.z = fmaxf(aHi.z, 0.f); aHi.w = fmaxf(aHi.w, 0.f);
        sH[na][2 * c] = aLo;
        sH[na][2 * c + 1] = aHi;
    }
    __syncthreads();
    if (t < 32) {
        int nd = blk0 + t;
        float ay = 0.f, az = 0.f;
#pragma unroll
        for (int kc = 0; kc < 8; ++kc) {
            float4 h4 = sH[t][kc];
            float4 f = sF[kc], r = sRF[kc];
            ay += h4.x * f.x + h4.y * f.y + h4.z * f.z + h4.w * f.w;
            az += h4.x * r.x + h4.y * r.y + h4.z * r.z + h4.w * r.w;
        }
        y4[nd] = ay;
        z4[nd] = az + sB;
    }
}

// ====== gather + pool + last-block finalize ======
__global__ __launch_bounds__(256) void gpool_final_kernel(
        const float* __restrict__ y4,
        const float* __restrict__ z4,
        const int* __restrict__ rowptr,
        const ushort_t* __restrict__ col,
        const int* __restrict__ batch,
        float* __restrict__ sums,
        float* __restrict__ counts,
        int* __restrict__ ctr,
        const float* __restrict__ bfc,
        float* __restrict__ out) {
    __shared__ float ls[NG];
    __shared__ float lc[NG];
    __shared__ int sDone;
    if (threadIdx.x < NG) { ls[threadIdx.x] = 0.f; lc[threadIdx.x] = 0.f; }
    if (threadIdx.x == 0) sDone = 0;
    __syncthreads();
    int nd = blockIdx.x * 256 + threadIdx.x;
    if (nd < NN) {
        float v = z4[nd];
        int beg = rowptr[nd], end = rowptr[nd + 1];
        int e = beg;
        for (; e + 4 <= end; e += 4) {
            v += (y4[col[e]] + y4[col[e + 1]]) + (y4[col[e + 2]] + y4[col[e + 3]]);
        }
        for (; e < end; ++e) v += y4[col[e]];
        int g = batch[nd];
        atomicAdd(&ls[g], v);
        atomicAdd(&lc[g], 1.f);
    }
    __syncthreads();
    if (threadIdx.x < NG && lc[threadIdx.x] > 0.f) {
        atomicAdd(&sums[threadIdx.x], ls[threadIdx.x]);
        atomicAdd(&counts[threadIdx.x], lc[threadIdx.x]);
    }
    __threadfence();
    __syncthreads();
    if (threadIdx.x == 0) {
        if (atomicAdd(ctr, 1) == (int)gridDim.x - 1) sDone = 1;
    }
    __syncthreads();
    if (sDone && threadIdx.x < NG) {
        float s = atomicAdd(&sums[threadIdx.x], 0.f);   // coherent read
        float c = atomicAdd(&counts[threadIdx.x], 0.f);
        c = fmaxf(c, 1.0f);
        out[threadIdx.x] = s / c + bfc[0];
    }
}

extern "C" void kernel_launch(void* const* d_in, const int* in_sizes, int n_in,
                              void* d_out, int out_size, void* d_ws, size_t ws_size,
                              hipStream_t stream) {
    const float* x       = (const float*)d_in[0];
    const int*   ei      = (const int*)d_in[1];
    const int*   batch   = (const int*)d_in[2];
    const float* W1_rel  = (const float*)d_in[3];
    const float* b1      = (const float*)d_in[4];
    const float* W1_root = (const float*)d_in[5];
    const float* W2_rel  = (const float*)d_in[6];
    const float* b2      = (const float*)d_in[7];
    const float* W2_root = (const float*)d_in[8];
    const float* W3_rel  = (const float*)d_in[9];
    const float* b3      = (const float*)d_in[10];
    const float* W3_root = (const float*)d_in[11];
    const float* W4_rel  = (const float*)d_in[12];
    const float* b4      = (const float*)d_in[13];
    const float* W4_root = (const float*)d_in[14];
    const float* Wfc     = (const float*)d_in[15];
    const float* bfc     = (const float*)d_in[16];
    float* out = (float*)d_out;

    const int* src = ei;        // edge_index[0]
    const int* dst = ei + NE;   // edge_index[1]

    // workspace layout
    uint2* h1b     = (uint2*)d_ws;                   // N x 32 (bf16 h1)
    float* bufZ    = (float*)(h1b + (size_t)NN * 32);// N x 64   (z2, fp32)
    float* z3      = bufZ + (size_t)NN * 64;         // N x 32   (fp32)
    float* y4      = z3 + (size_t)NN * 32;           // N
    float* z4      = y4 + NN;                        // N
    float* wf      = z4 + NN;                        // 65 (pad 68)
    int*   deg     = (int*)(wf + 68);                // N       -- zero block start
    float* sums    = (float*)(deg + NN);             // G
    float* counts  = sums + NG;                      // G
    int*   ctr     = (int*)(counts + NG);            // 1       -- zero block end
    int*   rowptr  = ctr + 1;                        // N+1
    int*   epos    = rowptr + NN + 1;                // E
    int*   bsum    = epos + NE;                      // SCAN_NB (pad 160)
    ushort_t* colu = (ushort_t*)(bsum + 160);        // E (2B)
    unsigned long long pa = (unsigned long long)(colu + NE);
    pa = (pa + 15ull) & ~15ull;
    uint2* xb      = (uint2*)pa;                     // N x 8  (bf16 x)
    unsigned int* y2f8 = (unsigned int*)(xb + (size_t)NN * 8);  // N x 16 (fp8 y2)
    uint2* y3b     = (uint2*)(y2f8 + (size_t)NN * 16);          // N x 8 (bf16 y3)

    const int NZ = NN + 2 * NG + 1;   // deg + sums + counts + ctr

    // ---- prep: zero scratch, convert x->bf16, fold Wfc through L4 ----
    prep_kernel<<<NN * 8 / 256, 256, 0, stream>>>(
        deg, NZ, (const float4*)x, xb, W4_rel, W4_root, b4, Wfc, wf);

    // ---- build CSR (dst-sorted reverse adjacency) ----
    hist_kernel<<<(NE + 255) / 256, 256, 0, stream>>>(dst, deg, epos);
    scan1_kernel<<<SCAN_NB, 256, 0, stream>>>(deg, rowptr, bsum);
    scan23_kernel<<<SCAN_NB, 256, 0, stream>>>(rowptr, bsum);
    fill_kernel<<<(NE + 255) / 256, 256, 0, stream>>>(src, dst, rowptr, epos, colu);

    // ---- Layer 1 fused: gather(xb) + conv 32->128 -> h1 bf16 ----
    fconv1_kernel<<<NN / 32, 256, 0, stream>>>(
        (const uint4*)xb, (const float4*)x, rowptr, colu,
        (const float4*)W1_rel, (const float4*)W1_root, (const float4*)b1,
        h1b);

    // ---- Layer 2 transform: h1(bf16) -> y2(fp8), z2(fp32) ----
    mmyz_kernel<<<NN / 32, 256, 0, stream>>>(
        h1b, (const float4*)W2_rel, (const float4*)W2_root,
        (const float4*)b2, y2f8, (float4*)bufZ);

    // ---- Layer 3 fused: gather(y2 fp8) + relu(z2+agg) + transform 64->32 ----
    fconv3_kernel<<<NN / 32, 256, 0, stream>>>(
        (const uint2*)y2f8, (const float4*)bufZ, rowptr, colu,
        (const float4*)W3_rel, (const float4*)W3_root, (const float4*)b3,
        y3b, (float4*)z3);

    // ---- Layer 4 fused: gather(y3 bf16) + relu(z3+agg) + folded dot ----
    fconv4_kernel<<<NN / 32, 256, 0, stream>>>(
        (const uint4*)y3b, (const float4*)z3, rowptr, colu, wf, y4, z4);

    // ---- final gather + pool + FC (last block finalizes) ----
    gpool_final_kernel<<<(NN + 255) / 256, 256, 0, stream>>>(
        y4, z4, rowptr, colu, batch, sums, counts, ctr, bfc, out);
}